// Round 4
// baseline (539.636 us; speedup 1.0000x reference)
//
#include <hip/hip_runtime.h>
#include <stdint.h>

#define D_IN 2048
#define D_H  512
#define WORDS 32            // D_IN / 64
#define NCH 8               // k-chunks of 256
#define BM  32              // rows per block (8 waves x 4 rows)

// Pack sign bits of W, transposed, in the permuted bit order the x-pack
// produces: word w = ch*4 + j (ch=0..7), bit p  <->  W[ch*256 + 4p + j][c].
__global__ __launch_bounds__(512) void pack_w_kernel(
    const float* __restrict__ W, unsigned long long* __restrict__ wb) {
  const int w = blockIdx.x;   // 0..31
  const int c = threadIdx.x;  // 0..511
  const int ch = w >> 2;
  const int j  = w & 3;
  unsigned long long bits = 0ull;
#pragma unroll 16
  for (int p = 0; p < 64; ++p) {
    float v = W[(size_t)(ch * 256 + 4 * p + j) * D_H + c];
    bits |= (unsigned long long)(v < 0.0f) << p;
  }
  wb[(size_t)w * D_H + c] = bits;
}

// Binary GEMM: W-bits in LDS (64KB half, swizzled, restaged once), X via
// SGPR ballots with depth-2 prefetch. K-loop has no barriers.
// LDS layout: word w' (0..15), col-pair p (0..255):
//   byte addr A(w',p) = w'*4096 + ((p*16) ^ (((p>>3)&7)<<4))
// Reader lane l needs pairs {2l, 2l+1, 128+2l, 129+2l} -> baseA/baseB plus
// immediate offsets {w'*4096, w'*4096+2048} (carry-free: offsets are
// multiples of 2048, XOR key lives in bits [6:4]).
__global__ __launch_bounds__(512, 4) void bgemm_kernel(
    const float* __restrict__ X,
    const unsigned long long* __restrict__ wb,
    const float* __restrict__ b, const float* __restrict__ beta,
    const float* __restrict__ mm, const float* __restrict__ mv,
    float* __restrict__ out) {
  __shared__ ulonglong2 wlds[4096];  // 64 KB
  char* lb = (char*)wlds;

  const int tid = threadIdx.x;
  const int wv  = tid >> 6;
  const int l   = tid & 63;
  const size_t m0 = (size_t)blockIdx.x * BM + (size_t)wv * 4;
  const float4* X4 = (const float4*)X;

  // swizzled read bases (bytes)
  const int key   = ((l >> 2) & 7) << 4;
  const int baseA = (l * 32) ^ key;
  const int baseB = baseA ^ 16;

  // staging: thread covers pair sp for words w' = 2i + sw0
  const int sp    = tid & 255;
  const int sw0   = tid >> 8;  // 0 or 1
  const int sbyte = (sp * 16) ^ (((sp >> 3) & 7) << 4);

  auto stage_half = [&](int half) {
#pragma unroll
    for (int i = 0; i < 8; ++i) {
      const int wp = 2 * i + sw0;
      ulonglong2 d = *(const ulonglong2*)(
          wb + ((size_t)(half * 16 + wp) << 9) + 2 * (size_t)sp);
      *(ulonglong2*)(lb + wp * 4096 + sbyte) = d;
    }
  };

  unsigned acc[4][8];
#pragma unroll
  for (int i = 0; i < 4; ++i)
#pragma unroll
    for (int j = 0; j < 8; ++j) acc[i][j] = 0u;

  float4 vx[2][4];
  unsigned long long sx[4][4];

  stage_half(0);
  // prologue: X chunks 0 and 1 in flight
#pragma unroll
  for (int i = 0; i < 4; ++i) vx[0][i] = X4[(m0 + i) * (D_IN / 4) + l];
#pragma unroll
  for (int i = 0; i < 4; ++i) vx[1][i] = X4[(m0 + i) * (D_IN / 4) + 64 + l];
#pragma unroll
  for (int i = 0; i < 4; ++i) {
    sx[i][0] = __ballot(vx[0][i].x < 0.0f);
    sx[i][1] = __ballot(vx[0][i].y < 0.0f);
    sx[i][2] = __ballot(vx[0][i].z < 0.0f);
    sx[i][3] = __ballot(vx[0][i].w < 0.0f);
  }
  __syncthreads();

#pragma unroll 2
  for (int g = 0; g < NCH; ++g) {
    if (g == 4) {  // restage second K-half (only barriers in the loop)
      __syncthreads();
      stage_half(1);
      __syncthreads();
    }
    if (g + 2 < NCH) {  // issue X loads 2 chunks ahead
#pragma unroll
      for (int i = 0; i < 4; ++i)
        vx[g & 1][i] = X4[(m0 + i) * (D_IN / 4) + (size_t)(g + 2) * 64 + l];
    }
    // compute chunk g from LDS
#pragma unroll
    for (int j = 0; j < 4; ++j) {
      const int wp = (g & 3) * 4 + j;
      ulonglong2 a0 = *(const ulonglong2*)(lb + baseA + wp * 4096);
      ulonglong2 a1 = *(const ulonglong2*)(lb + baseB + wp * 4096);
      ulonglong2 c0 = *(const ulonglong2*)(lb + baseA + wp * 4096 + 2048);
      ulonglong2 c1 = *(const ulonglong2*)(lb + baseB + wp * 4096 + 2048);
#pragma unroll
      for (int i = 0; i < 4; ++i) {
        const unsigned long long s = sx[i][j];
        acc[i][0] += (unsigned)__popcll(s ^ a0.x);
        acc[i][1] += (unsigned)__popcll(s ^ a0.y);
        acc[i][2] += (unsigned)__popcll(s ^ a1.x);
        acc[i][3] += (unsigned)__popcll(s ^ a1.y);
        acc[i][4] += (unsigned)__popcll(s ^ c0.x);
        acc[i][5] += (unsigned)__popcll(s ^ c0.y);
        acc[i][6] += (unsigned)__popcll(s ^ c1.x);
        acc[i][7] += (unsigned)__popcll(s ^ c1.y);
      }
    }
    if (g + 1 < NCH) {  // ballot-commit next chunk (loads issued 2 iters ago)
#pragma unroll
      for (int i = 0; i < 4; ++i) {
        const float4 v = vx[(g + 1) & 1][i];
        sx[i][0] = __ballot(v.x < 0.0f);
        sx[i][1] = __ballot(v.y < 0.0f);
        sx[i][2] = __ballot(v.z < 0.0f);
        sx[i][3] = __ballot(v.w < 0.0f);
      }
    }
  }

  // epilogue: y = (K - 2*diff) + b; out = (y - mean)/sqrt(var+eps) + beta
  {  // cols 4l .. 4l+3
    float4 bA = ((const float4*)b)[l];
    float4 mA = ((const float4*)mm)[l];
    float4 eA = ((const float4*)beta)[l];
    float4 vA = ((const float4*)mv)[l];
    float i0 = 1.0f / sqrtf(vA.x + 1e-3f);
    float i1 = 1.0f / sqrtf(vA.y + 1e-3f);
    float i2 = 1.0f / sqrtf(vA.z + 1e-3f);
    float i3 = 1.0f / sqrtf(vA.w + 1e-3f);
#pragma unroll
    for (int i = 0; i < 4; ++i) {
      float4 o;
      o.x = ((float)(D_IN - 2 * (int)acc[i][0]) + bA.x - mA.x) * i0 + eA.x;
      o.y = ((float)(D_IN - 2 * (int)acc[i][1]) + bA.y - mA.y) * i1 + eA.y;
      o.z = ((float)(D_IN - 2 * (int)acc[i][2]) + bA.z - mA.z) * i2 + eA.z;
      o.w = ((float)(D_IN - 2 * (int)acc[i][3]) + bA.w - mA.w) * i3 + eA.w;
      *(float4*)(out + (m0 + i) * D_H + 4 * (size_t)l) = o;
    }
  }
  {  // cols 256+4l .. 256+4l+3
    float4 bB = ((const float4*)b)[64 + l];
    float4 mB = ((const float4*)mm)[64 + l];
    float4 eB = ((const float4*)beta)[64 + l];
    float4 vB = ((const float4*)mv)[64 + l];
    float i0 = 1.0f / sqrtf(vB.x + 1e-3f);
    float i1 = 1.0f / sqrtf(vB.y + 1e-3f);
    float i2 = 1.0f / sqrtf(vB.z + 1e-3f);
    float i3 = 1.0f / sqrtf(vB.w + 1e-3f);
#pragma unroll
    for (int i = 0; i < 4; ++i) {
      float4 o;
      o.x = ((float)(D_IN - 2 * (int)acc[i][4]) + bB.x - mB.x) * i0 + eB.x;
      o.y = ((float)(D_IN - 2 * (int)acc[i][5]) + bB.y - mB.y) * i1 + eB.y;
      o.z = ((float)(D_IN - 2 * (int)acc[i][6]) + bB.z - mB.z) * i2 + eB.z;
      o.w = ((float)(D_IN - 2 * (int)acc[i][7]) + bB.w - mB.w) * i3 + eB.w;
      *(float4*)(out + (m0 + i) * D_H + 256 + 4 * (size_t)l) = o;
    }
  }
}

extern "C" void kernel_launch(void* const* d_in, const int* in_sizes, int n_in,
                              void* d_out, int out_size, void* d_ws, size_t ws_size,
                              hipStream_t stream) {
  const float* X    = (const float*)d_in[0];  // [32768, 2048]
  const float* W    = (const float*)d_in[1];  // [2048, 512]
  const float* b    = (const float*)d_in[2];  // [512]
  const float* beta = (const float*)d_in[3];  // [512]
  const float* mm   = (const float*)d_in[4];  // [512]
  const float* mv   = (const float*)d_in[5];  // [512]
  float* out = (float*)d_out;                 // [32768, 512]

  unsigned long long* wbits = (unsigned long long*)d_ws;  // 128 KB

  pack_w_kernel<<<dim3(WORDS), dim3(D_H), 0, stream>>>(W, wbits);

  const int M = in_sizes[0] / D_IN;  // 32768
  bgemm_kernel<<<dim3(M / BM), dim3(512), 0, stream>>>(X, wbits, b, beta, mm, mv, out);
}

// Round 5
// 305.032 us; speedup vs baseline: 1.7691x; 1.7691x over previous
//
#include <hip/hip_runtime.h>
#include <stdint.h>

#define D_IN 2048
#define D_H  512
#define NCH 8               // k-chunks of 256
#define BM  16              // rows per block (4 waves x 4 rows)

// Pack sign bits of W, transposed, in the permuted bit order the x-pack
// produces: word w = ch*4 + j (ch=0..7), bit p  <->  W[ch*256 + 4p + j][c].
__global__ __launch_bounds__(512) void pack_w_kernel(
    const float* __restrict__ W, unsigned long long* __restrict__ wb) {
  const int w = blockIdx.x;   // 0..31
  const int c = threadIdx.x;  // 0..511
  const int ch = w >> 2;
  const int j  = w & 3;
  unsigned long long bits = 0ull;
#pragma unroll 16
  for (int p = 0; p < 64; ++p) {
    float v = W[(size_t)(ch * 256 + 4 * p + j) * D_H + c];
    bits |= (unsigned long long)(v < 0.0f) << p;
  }
  wb[(size_t)w * D_H + c] = bits;
}

// Binary GEMM. W-bits double-buffered in LDS (compute waits = lgkmcnt only,
// decoupled from the vmcnt prefetch domain). X sign bits live in SGPRs via
// __ballot (wave owns its 4 rows). Per iter, vmcnt issue order is
// W(ch+1) then X(ch+1): W commit waits vmcnt(4) leaving X in flight;
// ballots consume X ~1200cy after issue. One barrier per chunk.
__global__ __launch_bounds__(256, 4) void bgemm_kernel(
    const float* __restrict__ X,
    const unsigned long long* __restrict__ wb,
    const float* __restrict__ b, const float* __restrict__ beta,
    const float* __restrict__ mm, const float* __restrict__ mv,
    float* __restrict__ out) {
  __shared__ unsigned long long wlds[2][4][512];  // 32 KB

  const int tid = threadIdx.x;
  const int wv  = tid >> 6;   // wave 0..3 (stages word wv; owns rows m0..m0+3)
  const int l   = tid & 63;
  const size_t m0 = (size_t)blockIdx.x * BM + (size_t)wv * 4;
  const float4* X4 = (const float4*)X;

  unsigned long long sx[4][4];   // wave-uniform -> SGPRs
  unsigned long long wst[8];     // staged W (regs, static idx)
  float4 v[4];                   // staged X (regs, static idx)

  unsigned acc[4][8];
#pragma unroll
  for (int i = 0; i < 4; ++i)
#pragma unroll
    for (int g = 0; g < 8; ++g) acc[i][g] = 0u;

  // ---- prologue: chunk 0 ----
  {
    const unsigned long long* src = wb + (size_t)wv * D_H;
#pragma unroll
    for (int g = 0; g < 8; ++g) wst[g] = src[64 * g + l];
#pragma unroll
    for (int i = 0; i < 4; ++i) v[i] = X4[(m0 + i) * (D_IN / 4) + l];
#pragma unroll
    for (int g = 0; g < 8; ++g) wlds[0][wv][64 * g + l] = wst[g];
#pragma unroll
    for (int i = 0; i < 4; ++i) {
      sx[i][0] = __ballot(v[i].x < 0.0f);
      sx[i][1] = __ballot(v[i].y < 0.0f);
      sx[i][2] = __ballot(v[i].z < 0.0f);
      sx[i][3] = __ballot(v[i].w < 0.0f);
    }
    __syncthreads();
  }

#pragma unroll 1
  for (int ch = 0; ch < NCH; ++ch) {
    const int buf = ch & 1;
    const bool more = (ch + 1 < NCH);

    if (more) {
      // W loads first (oldest in vmcnt), X loads second
      const unsigned long long* src = wb + ((size_t)(ch + 1) * 4 + wv) * D_H;
#pragma unroll
      for (int g = 0; g < 8; ++g) wst[g] = src[64 * g + l];
#pragma unroll
      for (int i = 0; i < 4; ++i)
        v[i] = X4[(m0 + i) * (D_IN / 4) + (size_t)(ch + 1) * 64 + l];
    }

    // ---- compute chunk ch from LDS buf (lgkmcnt domain only) ----
#pragma unroll
    for (int w = 0; w < 4; ++w) {
      unsigned long long wl0 = wlds[buf][w][0 * 64 + l];
      unsigned long long wl1 = wlds[buf][w][1 * 64 + l];
      unsigned long long wl2 = wlds[buf][w][2 * 64 + l];
      unsigned long long wl3 = wlds[buf][w][3 * 64 + l];
      unsigned long long wl4 = wlds[buf][w][4 * 64 + l];
      unsigned long long wl5 = wlds[buf][w][5 * 64 + l];
      unsigned long long wl6 = wlds[buf][w][6 * 64 + l];
      unsigned long long wl7 = wlds[buf][w][7 * 64 + l];
#pragma unroll
      for (int i = 0; i < 4; ++i) {
        const unsigned long long s = sx[i][w];
        acc[i][0] += (unsigned)__popcll(s ^ wl0);
        acc[i][1] += (unsigned)__popcll(s ^ wl1);
        acc[i][2] += (unsigned)__popcll(s ^ wl2);
        acc[i][3] += (unsigned)__popcll(s ^ wl3);
        acc[i][4] += (unsigned)__popcll(s ^ wl4);
        acc[i][5] += (unsigned)__popcll(s ^ wl5);
        acc[i][6] += (unsigned)__popcll(s ^ wl6);
        acc[i][7] += (unsigned)__popcll(s ^ wl7);
      }
    }

    if (more) {
      // commit W to the other buffer: waits vmcnt(4) (X stays in flight)
#pragma unroll
      for (int g = 0; g < 8; ++g) wlds[buf ^ 1][wv][64 * g + l] = wst[g];
      // ballots: waits vmcnt(0); X was issued a full compute phase ago
#pragma unroll
      for (int i = 0; i < 4; ++i) {
        sx[i][0] = __ballot(v[i].x < 0.0f);
        sx[i][1] = __ballot(v[i].y < 0.0f);
        sx[i][2] = __ballot(v[i].z < 0.0f);
        sx[i][3] = __ballot(v[i].w < 0.0f);
      }
    }
    __syncthreads();
  }

  // ---- epilogue: y = (K - 2*diff) + b; out = (y - mean)*rsqrt(var+eps) + beta
#pragma unroll
  for (int g = 0; g < 8; ++g) {
    const int c = 64 * g + l;
    const float bj  = b[c];
    const float mmj = mm[c];
    const float bej = beta[c];
    const float inv = rsqrtf(mv[c] + 1e-3f);
#pragma unroll
    for (int i = 0; i < 4; ++i) {
      out[(m0 + i) * D_H + c] =
          ((float)(D_IN - 2 * (int)acc[i][g]) + bj - mmj) * inv + bej;
    }
  }
}

extern "C" void kernel_launch(void* const* d_in, const int* in_sizes, int n_in,
                              void* d_out, int out_size, void* d_ws, size_t ws_size,
                              hipStream_t stream) {
  const float* X    = (const float*)d_in[0];  // [32768, 2048]
  const float* W    = (const float*)d_in[1];  // [2048, 512]
  const float* b    = (const float*)d_in[2];  // [512]
  const float* beta = (const float*)d_in[3];  // [512]
  const float* mm   = (const float*)d_in[4];  // [512]
  const float* mv   = (const float*)d_in[5];  // [512]
  float* out = (float*)d_out;                 // [32768, 512]

  unsigned long long* wbits = (unsigned long long*)d_ws;  // 128 KB

  pack_w_kernel<<<dim3(32), dim3(D_H), 0, stream>>>(W, wbits);

  const int M = in_sizes[0] / D_IN;  // 32768
  bgemm_kernel<<<dim3(M / BM), dim3(256), 0, stream>>>(X, wbits, b, beta, mm, mv, out);
}